// Round 7
// baseline (225.969 us; speedup 1.0000x reference)
//
#include <hip/hip_runtime.h>

// NRI MLP decoder, round 13: 512-thread blocks, 32 receivers (2 tiles)
// per block, grid 784. Session model (r9-r12): kernel is latency-bound
// at fixed wave concurrency -- all blocks co-resident, each wave ~93%
// stalled, issue ~57%; cutting VALU demand (r10), ILP (r9), LDS chains
// (r12) all flat; longer blocks (r11) regress. Remaining lever: resident
// waves 24 -> 32/CU (wave-slot cap). Per-wave work UNCHANGED (4 edge
// receivers, r10 64-VGPR body); 8 waves/block x 4 blocks/CU needs
// VGPR<=64 -> __launch_bounds__(512,8) (r10 proved this body fits 64
// clean; r7's spill came from clamping a ~110-reg body). Bonus: V
// staging shared by 2 tiles (was 4x redundant per (b,t), now 2x).
// LDS 22528B -> 7 blocks/CU cap, not binding vs 4-block wave cap.
// B=8, N=64, T=50 (49 used), D=4, H=64, K=2 (only relation i=1), E=4032.
// Grid = B*49*2 = 784 blocks, 512 threads (8 waves); wave w: receivers
// ni = w*4..w*4+3 of the block's 32. Edge fc2 GEMM + 3 node layers on
// mfma_f32_16x16x32_f16; fp32 accumulate everywhere.

#define NB 8
#define NN 64
#define NT 50
#define NTO 49
#define ND 4
#define NE 4032

typedef _Float16 f16x8 __attribute__((ext_vector_type(8)));
typedef _Float16 f16x4 __attribute__((ext_vector_type(4)));
typedef _Float16 f16x2 __attribute__((ext_vector_type(2)));
typedef float f32x4 __attribute__((ext_vector_type(4)));
typedef float f32x2 __attribute__((ext_vector_type(2)));

union Frag8 { unsigned u[4]; f16x8 f; f16x2 h[4]; };

__device__ __forceinline__ unsigned pk16(float lo, float hi) {
  return __builtin_bit_cast(unsigned, __builtin_amdgcn_cvt_pkrtz(lo, hi));
}

#define MFMA16(A, B, C) __builtin_amdgcn_mfma_f32_16x16x32_f16((A), (B), (C), 0, 0, 0)

__global__ __launch_bounds__(512, 8) void nri_fused_kernel(
    const float* __restrict__ inputs,   // (B,N,T,D)
    const float* __restrict__ rel_type, // (B,1,E,2)
    const float* __restrict__ fc1_w,    // (2,64,8)
    const float* __restrict__ fc1_b,    // (2,64)
    const float* __restrict__ fc2_w,    // (2,64,64)
    const float* __restrict__ fc2_b,    // (2,64)
    const float* __restrict__ out1_w,   // (64,68)
    const float* __restrict__ out1_b,   // (64)
    const float* __restrict__ out2_w,   // (64,64)
    const float* __restrict__ out2_b,   // (64)
    const float* __restrict__ out3_w,   // (4,64)
    const float* __restrict__ out3_b,   // (4)
    float* __restrict__ out)            // (B,N,49,4)
{
  // Manual LDS layout, 22528 B total (all sub-arrays 16B-aligned):
  //   [    0,  9216) Vh   f16[64*72]  V[s][k]          (edge only)
  //   [    0,  4608) H1L  f16[32*72]  alias, post-edge
  //   [ 4608,  9216) H2L  f16[32*72]  alias, post-edge
  //   [ 9216, 13312) Ph   f16[32*64]  U[n][k]+b1[k]
  //   [13312, 17408) Rl   f16[32*64]  rt[n][s]
  //   [17408, 17920) Xl   float4[32]
  //   [17920, 22528) AggL f16[32*72]
  __shared__ __align__(16) char smem[22528];
  _Float16* const Vh   = (_Float16*)(smem);
  _Float16* const H1L  = (_Float16*)(smem);
  _Float16* const H2L  = (_Float16*)(smem + 4608);
  _Float16* const Ph   = (_Float16*)(smem + 9216);
  _Float16* const Rl   = (_Float16*)(smem + 13312);
  float4*   const Xl   = (float4*)  (smem + 17408);
  _Float16* const AggL = (_Float16*)(smem + 17920);

  const int bid    = blockIdx.x;            // (b*49 + t)*2 + tile
  const int tile   = bid & 1;
  const int t      = (bid >> 1) % NTO;
  const int b      = bid / (2 * NTO);
  const int n_base = tile * 32;
  const int tid  = threadIdx.x;             // 0..511
  const int lane = tid & 63;
  const int w    = tid >> 6;                // 0..7
  const int wl   = w & 3;                   // node-phase column group
  const int h    = w >> 2;                  // node-phase row half
  const int q    = lane >> 4;
  const int r    = lane & 15;

  // ---------------- staging ----------------
  {
    const int k = lane;
    const float4 w1r = *(const float4*)(fc1_w + 512 + k * 8);
    const float4 w1s = *(const float4*)(fc1_w + 516 + k * 8);
    const float  b1k = fc1_b[64 + k];
    // V rows: 64 rows / 8 waves = 8 each, 2 batches of 4 (bounded load
    // concurrency, r10)
#pragma unroll 1
    for (int c = 0; c < 2; ++c) {
#pragma unroll
      for (int jj = 0; jj < 4; ++jj) {
        const int i = c * 32 + jj * 8 + w;
        const float4 x = *(const float4*)(inputs + ((b * NN + i) * NT + t) * ND);
        Vh[i * 72 + k] = (_Float16)(w1s.x*x.x + w1s.y*x.y + w1s.z*x.z + w1s.w*x.w);
      }
    }
#pragma unroll
    for (int ii = 0; ii < 4; ++ii) {             // P rows: 32 / 8 waves
      const int i = ii * 8 + w;
      const float4 x = *(const float4*)(inputs + ((b * NN + n_base + i) * NT + t) * ND);
      Ph[i * 64 + k] = (_Float16)(b1k + w1r.x*x.x + w1r.y*x.y + w1r.z*x.z + w1r.w*x.w);
    }
  }
#pragma unroll
  for (int ii = 0; ii < 4; ++ii) {               // rt: 2048 entries, f16
    const int idx = ii * 512 + tid;
    const int i = idx >> 6, s = idx & 63;
    const int n = n_base + i;
    const float v = (s == n) ? 0.f
                  : rel_type[(b * NE + n * 63 + (s < n ? s : s - 1)) * 2 + 1];
    Rl[idx] = (_Float16)v;
  }
  if (tid < 32)
    Xl[tid] = *(const float4*)(inputs + ((b * NN + n_base + tid) * NT + t) * ND);

  // ---- W2 (relation 1) f16 B-frags, register-resident
  Frag8 bfr[4][2];
  float b2l[4];
#pragma unroll
  for (int nt = 0; nt < 4; ++nt) {
    const int o = nt * 16 + r;
    b2l[nt] = fc2_b[64 + o];
#pragma unroll
    for (int ks = 0; ks < 2; ++ks) {
      const float* p = fc2_w + 4096 + o * 64 + ks * 32 + q * 8;
      const float4 c0 = *(const float4*)p;
      const float4 c1 = *(const float4*)(p + 4);
      bfr[nt][ks].u[0] = pk16(c0.x, c0.y);
      bfr[nt][ks].u[1] = pk16(c0.z, c0.w);
      bfr[nt][ks].u[2] = pk16(c1.x, c1.y);
      bfr[nt][ks].u[3] = pk16(c1.z, c1.w);
    }
  }
  __syncthreads();

  // ---------------- edge phase: wave w, 4 serial receivers ----------------
#pragma unroll 1
  for (int np = 0; np < 4; ++np) {
    const int ni = w * 4 + np;                   // 0..31
    Frag8 pa0, pa1;
    pa0.f = *(const f16x8*)(Ph + ni * 64 + q * 8);        // k = q*8..
    pa1.f = *(const f16x8*)(Ph + ni * 64 + 32 + q * 8);   // k = 32+q*8..

    float ag[4] = {0.f, 0.f, 0.f, 0.f};
#pragma unroll
    for (int st = 0; st < 4; ++st) {
      // V frags per st from LDS (64-VGPR diet: no hoist, no dbuf -- r10)
      Frag8 va0, va1;
      {
        const _Float16* vp = Vh + (st * 16 + r) * 72 + q * 8;
        va0.f = *(const f16x8*)vp;
        va1.f = *(const f16x8*)(vp + 32);
      }

      // rt for this st: senders st*16 + q*4 + {0..3}; broadcast across r
      const f16x4 rt4 = *(const f16x4*)(Rl + ni * 64 + st * 16 + q * 4);

      // h = relu(P + V), packed f16
      Frag8 a0, a1;
      const f16x2 z = {(_Float16)0.f, (_Float16)0.f};
#pragma unroll
      for (int j = 0; j < 4; ++j) {
        a0.h[j] = __builtin_elementwise_max((f16x2)(pa0.h[j] + va0.h[j]), z);
        a1.h[j] = __builtin_elementwise_max((f16x2)(pa1.h[j] + va1.h[j]), z);
      }

      const f32x4 z4 = {0.f, 0.f, 0.f, 0.f};
#pragma unroll
      for (int nt = 0; nt < 4; ++nt) {
        f32x4 d = {b2l[nt], b2l[nt], b2l[nt], b2l[nt]};
        d = MFMA16(a0.f, bfr[nt][0].f, d);
        d = MFMA16(a1.f, bfr[nt][1].f, d);
        // p = relu(m) f32 (packed max); ag += f16(rt)*f32(p) -> fma_mix
        const f32x4 p = __builtin_elementwise_max(d, z4);
        float s = ag[nt];
        s += (float)rt4[0] * p[0];
        s += (float)rt4[1] * p[1];
        s += (float)rt4[2] * p[2];
        s += (float)rt4[3] * p[3];
        ag[nt] = s;
      }
    }

    // reduce over q (each q-group holds a disjoint 16-sender partial)
#pragma unroll
    for (int nt = 0; nt < 4; ++nt) {
      float s = ag[nt];
      s += __shfl_xor(s, 16); s += __shfl_xor(s, 32);
      ag[nt] = s;
    }
    const float aval = (q == 0) ? ag[0] : (q == 1) ? ag[1] : (q == 2) ? ag[2] : ag[3];
    AggL[ni * 72 + lane] = (_Float16)aval;   // o = lane
  }

  // ---- node weights (independent of agg; overlap barrier drain)
  const int o = wl * 16 + r;
  Frag8 B1[2], B2[2];
#pragma unroll
  for (int ks = 0; ks < 2; ++ks) {
    const float* p1 = out1_w + o * 68 + 4 + ks * 32 + q * 8;
    const float4 c0 = *(const float4*)p1;
    const float4 c1 = *(const float4*)(p1 + 4);
    B1[ks].u[0] = pk16(c0.x, c0.y); B1[ks].u[1] = pk16(c0.z, c0.w);
    B1[ks].u[2] = pk16(c1.x, c1.y); B1[ks].u[3] = pk16(c1.z, c1.w);
    const float* p2 = out2_w + o * 64 + ks * 32 + q * 8;
    const float4 e0 = *(const float4*)p2;
    const float4 e1 = *(const float4*)(p2 + 4);
    B2[ks].u[0] = pk16(e0.x, e0.y); B2[ks].u[1] = pk16(e0.z, e0.w);
    B2[ks].u[2] = pk16(e1.x, e1.y); B2[ks].u[3] = pk16(e1.z, e1.w);
  }
  const float4 w1x = *(const float4*)(out1_w + o * 68);
  const float b1o = out1_b[o];
  const float b2o = out2_b[o];
  __syncthreads();   // AggL complete; Vh dead from here (H1L/H2L alias it)

  // ---------------- node phase (32 rows; half h = w>>2) ----------------
  // Layer 1: h1[n][o] = relu(b1 + x[n]·w1x + agg[n]·W1k[o])
  {
    Frag8 A0, A1;
    A0.f = *(const f16x8*)(AggL + (h * 16 + r) * 72 + q * 8);
    A1.f = *(const f16x8*)(AggL + (h * 16 + r) * 72 + 32 + q * 8);
    f32x4 d = {b1o, b1o, b1o, b1o};
    d = MFMA16(A0.f, B1[0].f, d);
    d = MFMA16(A1.f, B1[1].f, d);
#pragma unroll
    for (int reg = 0; reg < 4; ++reg) {
      const int n = h * 16 + q * 4 + reg;
      const float4 x = Xl[n];
      const float hv = d[reg] + x.x*w1x.x + x.y*w1x.y + x.z*w1x.z + x.w*w1x.w;
      H1L[n * 72 + o] = (_Float16)fmaxf(hv, 0.f);
    }
  }
  __syncthreads();

  // Layer 2: h2 = relu(b2 + h1·W2o^T)
  {
    Frag8 A0, A1;
    A0.f = *(const f16x8*)(H1L + (h * 16 + r) * 72 + q * 8);
    A1.f = *(const f16x8*)(H1L + (h * 16 + r) * 72 + 32 + q * 8);
    f32x4 d = {b2o, b2o, b2o, b2o};
    d = MFMA16(A0.f, B2[0].f, d);
    d = MFMA16(A1.f, B2[1].f, d);
#pragma unroll
    for (int reg = 0; reg < 4; ++reg) {
      const int n = h * 16 + q * 4 + reg;
      H2L[n * 72 + o] = (_Float16)fmaxf(d[reg], 0.f);
    }
  }
  __syncthreads();

  // Layer 3 (waves 0 and 4): delta[n][dm] = b3 + h2[n]·W3; out = x + delta
  if (wl == 0) {
    Frag8 B3[2];
#pragma unroll
    for (int ks = 0; ks < 2; ++ks) {
      const float* p3 = out3_w + (r & 3) * 64 + ks * 32 + q * 8;
      const float4 c0 = *(const float4*)p3;
      const float4 c1 = *(const float4*)(p3 + 4);
      B3[ks].u[0] = pk16(c0.x, c0.y); B3[ks].u[1] = pk16(c0.z, c0.w);
      B3[ks].u[2] = pk16(c1.x, c1.y); B3[ks].u[3] = pk16(c1.z, c1.w);
    }
    Frag8 A0, A1;
    A0.f = *(const f16x8*)(H2L + (h * 16 + r) * 72 + q * 8);
    A1.f = *(const f16x8*)(H2L + (h * 16 + r) * 72 + 32 + q * 8);
    const float b3o = out3_b[r & 3];
    f32x4 d = {b3o, b3o, b3o, b3o};
    d = MFMA16(A0.f, B3[0].f, d);
    d = MFMA16(A1.f, B3[1].f, d);
    if (r < 4) {  // valid cols; rows h*16 + q*4 + reg all valid
      const float* xf = (const float*)Xl;
#pragma unroll
      for (int reg = 0; reg < 4; ++reg) {
        const int n = h * 16 + q * 4 + reg;
        out[((b * NN + n_base + n) * NTO + t) * ND + r] = xf[n * 4 + r] + d[reg];
      }
    }
  }
}

extern "C" void kernel_launch(void* const* d_in, const int* in_sizes, int n_in,
                              void* d_out, int out_size, void* d_ws, size_t ws_size,
                              hipStream_t stream) {
  const float* inputs   = (const float*)d_in[0];
  const float* rel_type = (const float*)d_in[1];
  const float* fc1_w  = (const float*)d_in[4];
  const float* fc1_b  = (const float*)d_in[5];
  const float* fc2_w  = (const float*)d_in[6];
  const float* fc2_b  = (const float*)d_in[7];
  const float* out1_w = (const float*)d_in[8];
  const float* out1_b = (const float*)d_in[9];
  const float* out2_w = (const float*)d_in[10];
  const float* out2_b = (const float*)d_in[11];
  const float* out3_w = (const float*)d_in[12];
  const float* out3_b = (const float*)d_in[13];
  float* out = (float*)d_out;

  nri_fused_kernel<<<NB * NTO * 2, 512, 0, stream>>>(
      inputs, rel_type, fc1_w, fc1_b, fc2_w, fc2_b,
      out1_w, out1_b, out2_w, out2_b, out3_w, out3_b, out);
}

// Round 8
// 119.011 us; speedup vs baseline: 1.8987x; 1.8987x over previous
//
#include <hip/hip_runtime.h>

// NRI MLP decoder, round 14: r13's 512-thread structure with the
// launch-bounds clamp FIXED. Empirical compiler rule (r7, r10, r13):
// VGPR cap = 256 / min_waves_per_eu. (512,8) -> cap 32 -> the ~60-reg
// body spilled 261MB of scratch (r13's 149us disaster). (512,4) -> cap
// 64 = the allocation r10 proved this body fits with zero spill.
// Why retry: r13's wreckage carried a diagnostic -- OccupancyPercent 49%
// at 24.5 theoretical waves/CU (512-thr blocks) vs r10's 25% at the SAME
// 24.5 theoretical waves/CU (256-thr blocks). Only ~2 workgroups/CU get
// packed regardless of VGPR/LDS headroom, so waves/CU = 2 x block-waves:
// 256-thr -> 8 resident (every flat round r9-r12 ran here), 512-thr ->
// 16. Doubling block size is the one lever that raises resident waves.
// Grid = B*49*2 = 784 blocks, 512 threads (8 waves); wave w: receivers
// ni = w*4..w*4+3 of the block's 32 (2 tiles share one V staging).
// B=8, N=64, T=50 (49 used), D=4, H=64, K=2 (only relation i=1), E=4032.
// Edge fc2 GEMM + 3 node layers on mfma_f32_16x16x32_f16; fp32 acc.

#define NB 8
#define NN 64
#define NT 50
#define NTO 49
#define ND 4
#define NE 4032

typedef _Float16 f16x8 __attribute__((ext_vector_type(8)));
typedef _Float16 f16x4 __attribute__((ext_vector_type(4)));
typedef _Float16 f16x2 __attribute__((ext_vector_type(2)));
typedef float f32x4 __attribute__((ext_vector_type(4)));
typedef float f32x2 __attribute__((ext_vector_type(2)));

union Frag8 { unsigned u[4]; f16x8 f; f16x2 h[4]; };

__device__ __forceinline__ unsigned pk16(float lo, float hi) {
  return __builtin_bit_cast(unsigned, __builtin_amdgcn_cvt_pkrtz(lo, hi));
}

#define MFMA16(A, B, C) __builtin_amdgcn_mfma_f32_16x16x32_f16((A), (B), (C), 0, 0, 0)

__global__ __launch_bounds__(512, 4) void nri_fused_kernel(
    const float* __restrict__ inputs,   // (B,N,T,D)
    const float* __restrict__ rel_type, // (B,1,E,2)
    const float* __restrict__ fc1_w,    // (2,64,8)
    const float* __restrict__ fc1_b,    // (2,64)
    const float* __restrict__ fc2_w,    // (2,64,64)
    const float* __restrict__ fc2_b,    // (2,64)
    const float* __restrict__ out1_w,   // (64,68)
    const float* __restrict__ out1_b,   // (64)
    const float* __restrict__ out2_w,   // (64,64)
    const float* __restrict__ out2_b,   // (64)
    const float* __restrict__ out3_w,   // (4,64)
    const float* __restrict__ out3_b,   // (4)
    float* __restrict__ out)            // (B,N,49,4)
{
  // Manual LDS layout, 22528 B total (all sub-arrays 16B-aligned):
  //   [    0,  9216) Vh   f16[64*72]  V[s][k]          (edge only)
  //   [    0,  4608) H1L  f16[32*72]  alias, post-edge
  //   [ 4608,  9216) H2L  f16[32*72]  alias, post-edge
  //   [ 9216, 13312) Ph   f16[32*64]  U[n][k]+b1[k]
  //   [13312, 17408) Rl   f16[32*64]  rt[n][s]
  //   [17408, 17920) Xl   float4[32]
  //   [17920, 22528) AggL f16[32*72]
  __shared__ __align__(16) char smem[22528];
  _Float16* const Vh   = (_Float16*)(smem);
  _Float16* const H1L  = (_Float16*)(smem);
  _Float16* const H2L  = (_Float16*)(smem + 4608);
  _Float16* const Ph   = (_Float16*)(smem + 9216);
  _Float16* const Rl   = (_Float16*)(smem + 13312);
  float4*   const Xl   = (float4*)  (smem + 17408);
  _Float16* const AggL = (_Float16*)(smem + 17920);

  const int bid    = blockIdx.x;            // (b*49 + t)*2 + tile
  const int tile   = bid & 1;
  const int t      = (bid >> 1) % NTO;
  const int b      = bid / (2 * NTO);
  const int n_base = tile * 32;
  const int tid  = threadIdx.x;             // 0..511
  const int lane = tid & 63;
  const int w    = tid >> 6;                // 0..7
  const int wl   = w & 3;                   // node-phase column group
  const int h    = w >> 2;                  // node-phase row half
  const int q    = lane >> 4;
  const int r    = lane & 15;

  // ---------------- staging ----------------
  {
    const int k = lane;
    const float4 w1r = *(const float4*)(fc1_w + 512 + k * 8);
    const float4 w1s = *(const float4*)(fc1_w + 516 + k * 8);
    const float  b1k = fc1_b[64 + k];
    // V rows: 64 rows / 8 waves = 8 each, 2 batches of 4 (bounded load
    // concurrency, r10)
#pragma unroll 1
    for (int c = 0; c < 2; ++c) {
#pragma unroll
      for (int jj = 0; jj < 4; ++jj) {
        const int i = c * 32 + jj * 8 + w;
        const float4 x = *(const float4*)(inputs + ((b * NN + i) * NT + t) * ND);
        Vh[i * 72 + k] = (_Float16)(w1s.x*x.x + w1s.y*x.y + w1s.z*x.z + w1s.w*x.w);
      }
    }
#pragma unroll
    for (int ii = 0; ii < 4; ++ii) {             // P rows: 32 / 8 waves
      const int i = ii * 8 + w;
      const float4 x = *(const float4*)(inputs + ((b * NN + n_base + i) * NT + t) * ND);
      Ph[i * 64 + k] = (_Float16)(b1k + w1r.x*x.x + w1r.y*x.y + w1r.z*x.z + w1r.w*x.w);
    }
  }
#pragma unroll
  for (int ii = 0; ii < 4; ++ii) {               // rt: 2048 entries, f16
    const int idx = ii * 512 + tid;
    const int i = idx >> 6, s = idx & 63;
    const int n = n_base + i;
    const float v = (s == n) ? 0.f
                  : rel_type[(b * NE + n * 63 + (s < n ? s : s - 1)) * 2 + 1];
    Rl[idx] = (_Float16)v;
  }
  if (tid < 32)
    Xl[tid] = *(const float4*)(inputs + ((b * NN + n_base + tid) * NT + t) * ND);

  // ---- W2 (relation 1) f16 B-frags, register-resident
  Frag8 bfr[4][2];
  float b2l[4];
#pragma unroll
  for (int nt = 0; nt < 4; ++nt) {
    const int o = nt * 16 + r;
    b2l[nt] = fc2_b[64 + o];
#pragma unroll
    for (int ks = 0; ks < 2; ++ks) {
      const float* p = fc2_w + 4096 + o * 64 + ks * 32 + q * 8;
      const float4 c0 = *(const float4*)p;
      const float4 c1 = *(const float4*)(p + 4);
      bfr[nt][ks].u[0] = pk16(c0.x, c0.y);
      bfr[nt][ks].u[1] = pk16(c0.z, c0.w);
      bfr[nt][ks].u[2] = pk16(c1.x, c1.y);
      bfr[nt][ks].u[3] = pk16(c1.z, c1.w);
    }
  }
  __syncthreads();

  // ---------------- edge phase: wave w, 4 serial receivers ----------------
#pragma unroll 1
  for (int np = 0; np < 4; ++np) {
    const int ni = w * 4 + np;                   // 0..31
    Frag8 pa0, pa1;
    pa0.f = *(const f16x8*)(Ph + ni * 64 + q * 8);        // k = q*8..
    pa1.f = *(const f16x8*)(Ph + ni * 64 + 32 + q * 8);   // k = 32+q*8..

    float ag[4] = {0.f, 0.f, 0.f, 0.f};
#pragma unroll
    for (int st = 0; st < 4; ++st) {
      // V frags per st from LDS (64-VGPR diet: no hoist, no dbuf -- r10)
      Frag8 va0, va1;
      {
        const _Float16* vp = Vh + (st * 16 + r) * 72 + q * 8;
        va0.f = *(const f16x8*)vp;
        va1.f = *(const f16x8*)(vp + 32);
      }

      // rt for this st: senders st*16 + q*4 + {0..3}; broadcast across r
      const f16x4 rt4 = *(const f16x4*)(Rl + ni * 64 + st * 16 + q * 4);

      // h = relu(P + V), packed f16
      Frag8 a0, a1;
      const f16x2 z = {(_Float16)0.f, (_Float16)0.f};
#pragma unroll
      for (int j = 0; j < 4; ++j) {
        a0.h[j] = __builtin_elementwise_max((f16x2)(pa0.h[j] + va0.h[j]), z);
        a1.h[j] = __builtin_elementwise_max((f16x2)(pa1.h[j] + va1.h[j]), z);
      }

      const f32x4 z4 = {0.f, 0.f, 0.f, 0.f};
#pragma unroll
      for (int nt = 0; nt < 4; ++nt) {
        f32x4 d = {b2l[nt], b2l[nt], b2l[nt], b2l[nt]};
        d = MFMA16(a0.f, bfr[nt][0].f, d);
        d = MFMA16(a1.f, bfr[nt][1].f, d);
        // p = relu(m) f32 (packed max); ag += f16(rt)*f32(p) -> fma_mix
        const f32x4 p = __builtin_elementwise_max(d, z4);
        float s = ag[nt];
        s += (float)rt4[0] * p[0];
        s += (float)rt4[1] * p[1];
        s += (float)rt4[2] * p[2];
        s += (float)rt4[3] * p[3];
        ag[nt] = s;
      }
    }

    // reduce over q (each q-group holds a disjoint 16-sender partial)
#pragma unroll
    for (int nt = 0; nt < 4; ++nt) {
      float s = ag[nt];
      s += __shfl_xor(s, 16); s += __shfl_xor(s, 32);
      ag[nt] = s;
    }
    const float aval = (q == 0) ? ag[0] : (q == 1) ? ag[1] : (q == 2) ? ag[2] : ag[3];
    AggL[ni * 72 + lane] = (_Float16)aval;   // o = lane
  }

  // ---- node weights (independent of agg; overlap barrier drain)
  const int o = wl * 16 + r;
  Frag8 B1[2], B2[2];
#pragma unroll
  for (int ks = 0; ks < 2; ++ks) {
    const float* p1 = out1_w + o * 68 + 4 + ks * 32 + q * 8;
    const float4 c0 = *(const float4*)p1;
    const float4 c1 = *(const float4*)(p1 + 4);
    B1[ks].u[0] = pk16(c0.x, c0.y); B1[ks].u[1] = pk16(c0.z, c0.w);
    B1[ks].u[2] = pk16(c1.x, c1.y); B1[ks].u[3] = pk16(c1.z, c1.w);
    const float* p2 = out2_w + o * 64 + ks * 32 + q * 8;
    const float4 e0 = *(const float4*)p2;
    const float4 e1 = *(const float4*)(p2 + 4);
    B2[ks].u[0] = pk16(e0.x, e0.y); B2[ks].u[1] = pk16(e0.z, e0.w);
    B2[ks].u[2] = pk16(e1.x, e1.y); B2[ks].u[3] = pk16(e1.z, e1.w);
  }
  const float4 w1x = *(const float4*)(out1_w + o * 68);
  const float b1o = out1_b[o];
  const float b2o = out2_b[o];
  __syncthreads();   // AggL complete; Vh dead from here (H1L/H2L alias it)

  // ---------------- node phase (32 rows; half h = w>>2) ----------------
  // Layer 1: h1[n][o] = relu(b1 + x[n]·w1x + agg[n]·W1k[o])
  {
    Frag8 A0, A1;
    A0.f = *(const f16x8*)(AggL + (h * 16 + r) * 72 + q * 8);
    A1.f = *(const f16x8*)(AggL + (h * 16 + r) * 72 + 32 + q * 8);
    f32x4 d = {b1o, b1o, b1o, b1o};
    d = MFMA16(A0.f, B1[0].f, d);
    d = MFMA16(A1.f, B1[1].f, d);
#pragma unroll
    for (int reg = 0; reg < 4; ++reg) {
      const int n = h * 16 + q * 4 + reg;
      const float4 x = Xl[n];
      const float hv = d[reg] + x.x*w1x.x + x.y*w1x.y + x.z*w1x.z + x.w*w1x.w;
      H1L[n * 72 + o] = (_Float16)fmaxf(hv, 0.f);
    }
  }
  __syncthreads();

  // Layer 2: h2 = relu(b2 + h1·W2o^T)
  {
    Frag8 A0, A1;
    A0.f = *(const f16x8*)(H1L + (h * 16 + r) * 72 + q * 8);
    A1.f = *(const f16x8*)(H1L + (h * 16 + r) * 72 + 32 + q * 8);
    f32x4 d = {b2o, b2o, b2o, b2o};
    d = MFMA16(A0.f, B2[0].f, d);
    d = MFMA16(A1.f, B2[1].f, d);
#pragma unroll
    for (int reg = 0; reg < 4; ++reg) {
      const int n = h * 16 + q * 4 + reg;
      H2L[n * 72 + o] = (_Float16)fmaxf(d[reg], 0.f);
    }
  }
  __syncthreads();

  // Layer 3 (waves 0 and 4): delta[n][dm] = b3 + h2[n]·W3; out = x + delta
  if (wl == 0) {
    Frag8 B3[2];
#pragma unroll
    for (int ks = 0; ks < 2; ++ks) {
      const float* p3 = out3_w + (r & 3) * 64 + ks * 32 + q * 8;
      const float4 c0 = *(const float4*)p3;
      const float4 c1 = *(const float4*)(p3 + 4);
      B3[ks].u[0] = pk16(c0.x, c0.y); B3[ks].u[1] = pk16(c0.z, c0.w);
      B3[ks].u[2] = pk16(c1.x, c1.y); B3[ks].u[3] = pk16(c1.z, c1.w);
    }
    Frag8 A0, A1;
    A0.f = *(const f16x8*)(H2L + (h * 16 + r) * 72 + q * 8);
    A1.f = *(const f16x8*)(H2L + (h * 16 + r) * 72 + 32 + q * 8);
    const float b3o = out3_b[r & 3];
    f32x4 d = {b3o, b3o, b3o, b3o};
    d = MFMA16(A0.f, B3[0].f, d);
    d = MFMA16(A1.f, B3[1].f, d);
    if (r < 4) {  // valid cols; rows h*16 + q*4 + reg all valid
      const float* xf = (const float*)Xl;
#pragma unroll
      for (int reg = 0; reg < 4; ++reg) {
        const int n = h * 16 + q * 4 + reg;
        out[((b * NN + n_base + n) * NTO + t) * ND + r] = xf[n * 4 + r] + d[reg];
      }
    }
  }
}

extern "C" void kernel_launch(void* const* d_in, const int* in_sizes, int n_in,
                              void* d_out, int out_size, void* d_ws, size_t ws_size,
                              hipStream_t stream) {
  const float* inputs   = (const float*)d_in[0];
  const float* rel_type = (const float*)d_in[1];
  const float* fc1_w  = (const float*)d_in[4];
  const float* fc1_b  = (const float*)d_in[5];
  const float* fc2_w  = (const float*)d_in[6];
  const float* fc2_b  = (const float*)d_in[7];
  const float* out1_w = (const float*)d_in[8];
  const float* out1_b = (const float*)d_in[9];
  const float* out2_w = (const float*)d_in[10];
  const float* out2_b = (const float*)d_in[11];
  const float* out3_w = (const float*)d_in[12];
  const float* out3_b = (const float*)d_in[13];
  float* out = (float*)d_out;

  nri_fused_kernel<<<NB * NTO * 2, 512, 0, stream>>>(
      inputs, rel_type, fc1_w, fc1_b, fc2_w, fc2_b,
      out1_w, out1_b, out2_w, out2_b, out3_w, out3_b, out);
}

// Round 10
// 112.039 us; speedup vs baseline: 2.0169x; 1.0622x over previous
//
#include <hip/hip_runtime.h>

// NRI MLP decoder, round 16: RESUBMIT of round 15 (bench infra failed
// twice; no data). r8 base (fastest measured kernel, <39.4us) + T5
// s_setprio around the edge-phase MFMA/epilogue cluster. Session ledger
// r8-r14: VALU cut, ILP pairing, bank-conflict halving, LDS-chain
// removal, VGPR tier, longer blocks, wider blocks -- all falsified;
// healthy builds pin at 38.5-40us, ~77% per-wave stall, bench = kernel +
// ~74us fixed fill overhead. T5's regime (wave role diversity) matches
// the edge phase: no barrier for its whole span, so co-resident waves
// drift across staging/MFMA/epilogue/reduce phases; setprio(1) lets
// compute-phase waves issue ahead of staging-phase address VALU
// (learn_hip m191: +4-7% attn; m190: null only under barrier lockstep).
// Single delta vs r8; numerics identical.
// B=8, N=64, T=50 (49 used), D=4, H=64, K=2 (only relation i=1), E=4032.
// Grid = B*49*4 = 1568 blocks, 256 threads (4 waves); block = (b,t,16
// receivers); wave = 4 receivers serial. Edge fc2 GEMM + 3 node layers on
// mfma_f32_16x16x32_f16; fp32 accumulate everywhere.

#define NB 8
#define NN 64
#define NT 50
#define NTO 49
#define ND 4
#define NE 4032

typedef _Float16 f16x8 __attribute__((ext_vector_type(8)));
typedef _Float16 f16x4 __attribute__((ext_vector_type(4)));
typedef _Float16 f16x2 __attribute__((ext_vector_type(2)));
typedef float f32x4 __attribute__((ext_vector_type(4)));
typedef float f32x2 __attribute__((ext_vector_type(2)));

union Frag8 { unsigned u[4]; f16x8 f; f16x2 h[4]; };

__device__ __forceinline__ unsigned pk16(float lo, float hi) {
  return __builtin_bit_cast(unsigned, __builtin_amdgcn_cvt_pkrtz(lo, hi));
}

#define MFMA16(A, B, C) __builtin_amdgcn_mfma_f32_16x16x32_f16((A), (B), (C), 0, 0, 0)

__global__ __launch_bounds__(256) void nri_fused_kernel(
    const float* __restrict__ inputs,   // (B,N,T,D)
    const float* __restrict__ rel_type, // (B,1,E,2)
    const float* __restrict__ fc1_w,    // (2,64,8)
    const float* __restrict__ fc1_b,    // (2,64)
    const float* __restrict__ fc2_w,    // (2,64,64)
    const float* __restrict__ fc2_b,    // (2,64)
    const float* __restrict__ out1_w,   // (64,68)
    const float* __restrict__ out1_b,   // (64)
    const float* __restrict__ out2_w,   // (64,64)
    const float* __restrict__ out2_b,   // (64)
    const float* __restrict__ out3_w,   // (4,64)
    const float* __restrict__ out3_b,   // (4)
    float* __restrict__ out)            // (B,N,49,4)
{
  // Manual LDS layout, 15872 B total (all sub-arrays 16B-aligned):
  //   [    0,  9216) Vh   f16[64*72]  V[s][k]          (edge only)
  //   [    0,  2304) H1L  f16[16*72]  alias, post-edge
  //   [ 4608,  6912) H2L  f16[16*72]  alias, post-edge
  //   [ 9216, 11264) Ph   f16[16*64]  U[n][k]+b1[k]
  //   [11264, 13312) Rl   f16[16*64]  rt[n][s]
  //   [13312, 13568) Xl   float4[16]
  //   [13568, 15872) AggL f16[16*72]
  __shared__ __align__(16) char smem[15872];
  _Float16* const Vh   = (_Float16*)(smem);
  _Float16* const H1L  = (_Float16*)(smem);
  _Float16* const H2L  = (_Float16*)(smem + 4608);
  _Float16* const Ph   = (_Float16*)(smem + 9216);
  _Float16* const Rl   = (_Float16*)(smem + 11264);
  float4*   const Xl   = (float4*)  (smem + 13312);
  _Float16* const AggL = (_Float16*)(smem + 13568);

  const int bid    = blockIdx.x;
  const int tile   = bid & 3;
  const int t      = (bid >> 2) % NTO;
  const int b      = bid / (4 * NTO);
  const int n_base = tile * 16;
  const int tid  = threadIdx.x;
  const int lane = tid & 63;
  const int w    = tid >> 6;
  const int q    = lane >> 4;
  const int r    = lane & 15;

  // ---------------- staging ----------------
  {
    const int k = lane;
    const float4 w1r = *(const float4*)(fc1_w + 512 + k * 8);
    const float4 w1s = *(const float4*)(fc1_w + 516 + k * 8);
    const float  b1k = fc1_b[64 + k];
#pragma unroll
    for (int ii = 0; ii < 16; ++ii) {            // V rows i = w, w+4, ...
      const int i = ii * 4 + w;
      const float4 x = *(const float4*)(inputs + ((b * NN + i) * NT + t) * ND);
      Vh[i * 72 + k] = (_Float16)(w1s.x*x.x + w1s.y*x.y + w1s.z*x.z + w1s.w*x.w);
    }
#pragma unroll
    for (int ii = 0; ii < 4; ++ii) {             // P rows (stride 64)
      const int i = ii * 4 + w;
      const float4 x = *(const float4*)(inputs + ((b * NN + n_base + i) * NT + t) * ND);
      Ph[i * 64 + k] = (_Float16)(b1k + w1r.x*x.x + w1r.y*x.y + w1r.z*x.z + w1r.w*x.w);
    }
  }
#pragma unroll
  for (int ii = 0; ii < 4; ++ii) {               // rt: 1024 entries, f16
    const int idx = ii * 256 + tid;
    const int i = idx >> 6, s = idx & 63;
    const int n = n_base + i;
    const float v = (s == n) ? 0.f
                  : rel_type[(b * NE + n * 63 + (s < n ? s : s - 1)) * 2 + 1];
    Rl[idx] = (_Float16)v;
  }
  if (tid < 16)
    Xl[tid] = *(const float4*)(inputs + ((b * NN + n_base + tid) * NT + t) * ND);

  // ---- W2 (relation 1) f16 B-frags, register-resident
  Frag8 bfr[4][2];
  float b2l[4];
#pragma unroll
  for (int nt = 0; nt < 4; ++nt) {
    const int o = nt * 16 + r;
    b2l[nt] = fc2_b[64 + o];
#pragma unroll
    for (int ks = 0; ks < 2; ++ks) {
      const float* p = fc2_w + 4096 + o * 64 + ks * 32 + q * 8;
      const float4 c0 = *(const float4*)p;
      const float4 c1 = *(const float4*)(p + 4);
      bfr[nt][ks].u[0] = pk16(c0.x, c0.y);
      bfr[nt][ks].u[1] = pk16(c0.z, c0.w);
      bfr[nt][ks].u[2] = pk16(c1.x, c1.y);
      bfr[nt][ks].u[3] = pk16(c1.z, c1.w);
    }
  }
  __syncthreads();

  // ---------------- edge phase: wave w, 4 serial receivers ----------------
#pragma unroll 1
  for (int np = 0; np < 4; ++np) {
    const int ni = w * 4 + np;
    Frag8 pa0, pa1;
    pa0.f = *(const f16x8*)(Ph + ni * 64 + q * 8);        // k = q*8..
    pa1.f = *(const f16x8*)(Ph + ni * 64 + 32 + q * 8);   // k = 32+q*8..

    // preload st=0 V frags
    Frag8 va0, va1;
    {
      const _Float16* vp = Vh + r * 72 + q * 8;
      va0.f = *(const f16x8*)vp;
      va1.f = *(const f16x8*)(vp + 32);
    }

    float ag[4] = {0.f, 0.f, 0.f, 0.f};
#pragma unroll
    for (int st = 0; st < 4; ++st) {
      Frag8 nva0, nva1;
      if (st < 3) {  // prefetch next st's V frags
        const _Float16* vp = Vh + ((st + 1) * 16 + r) * 72 + q * 8;
        nva0.f = *(const f16x8*)vp;
        nva1.f = *(const f16x8*)(vp + 32);
      }

      // rt for this st: senders st*16 + q*4 + {0..3}; broadcast across r
      // (16 lanes same address) -> conflict-free 8B ds_read.
      const f16x4 rt4 = *(const f16x4*)(Rl + ni * 64 + st * 16 + q * 4);

      // h = relu(P + V), packed f16
      Frag8 a0, a1;
      const f16x2 z = {(_Float16)0.f, (_Float16)0.f};
#pragma unroll
      for (int j = 0; j < 4; ++j) {
        a0.h[j] = __builtin_elementwise_max((f16x2)(pa0.h[j] + va0.h[j]), z);
        a1.h[j] = __builtin_elementwise_max((f16x2)(pa1.h[j] + va1.h[j]), z);
      }

      // T5: favor this wave while it drains the MFMA+epilogue cluster;
      // co-resident waves in staging/reduce phases yield issue slots.
      __builtin_amdgcn_s_setprio(1);
      const f32x4 z4 = {0.f, 0.f, 0.f, 0.f};
#pragma unroll
      for (int nt = 0; nt < 4; ++nt) {
        f32x4 d = {b2l[nt], b2l[nt], b2l[nt], b2l[nt]};
        d = MFMA16(a0.f, bfr[nt][0].f, d);
        d = MFMA16(a1.f, bfr[nt][1].f, d);
        // p = relu(m) in f32 (packed max); ag += f16(rt) * f32(p) -> fma_mix
        const f32x4 p = __builtin_elementwise_max(d, z4);
        float s = ag[nt];
        s += (float)rt4[0] * p[0];
        s += (float)rt4[1] * p[1];
        s += (float)rt4[2] * p[2];
        s += (float)rt4[3] * p[3];
        ag[nt] = s;
      }
      __builtin_amdgcn_s_setprio(0);

      va0 = nva0; va1 = nva1;
    }

    // reduce over q (each q-group holds a disjoint 16-sender partial)
#pragma unroll
    for (int nt = 0; nt < 4; ++nt) {
      float s = ag[nt];
      s += __shfl_xor(s, 16); s += __shfl_xor(s, 32);
      ag[nt] = s;
    }
    const float aval = (q == 0) ? ag[0] : (q == 1) ? ag[1] : (q == 2) ? ag[2] : ag[3];
    AggL[ni * 72 + lane] = (_Float16)aval;   // o = lane
  }

  // ---- node weights (independent of agg; overlap barrier drain)
  const int o = w * 16 + r;
  Frag8 B1[2], B2[2];
#pragma unroll
  for (int ks = 0; ks < 2; ++ks) {
    const float* p1 = out1_w + o * 68 + 4 + ks * 32 + q * 8;
    const float4 c0 = *(const float4*)p1;
    const float4 c1 = *(const float4*)(p1 + 4);
    B1[ks].u[0] = pk16(c0.x, c0.y); B1[ks].u[1] = pk16(c0.z, c0.w);
    B1[ks].u[2] = pk16(c1.x, c1.y); B1[ks].u[3] = pk16(c1.z, c1.w);
    const float* p2 = out2_w + o * 64 + ks * 32 + q * 8;
    const float4 e0 = *(const float4*)p2;
    const float4 e1 = *(const float4*)(p2 + 4);
    B2[ks].u[0] = pk16(e0.x, e0.y); B2[ks].u[1] = pk16(e0.z, e0.w);
    B2[ks].u[2] = pk16(e1.x, e1.y); B2[ks].u[3] = pk16(e1.z, e1.w);
  }
  const float4 w1x = *(const float4*)(out1_w + o * 68);
  const float b1o = out1_b[o];
  const float b2o = out2_b[o];
  __syncthreads();   // AggL complete; Vh dead from here (H1L/H2L alias it)

  // ---------------- node phase (16 rows) ----------------
  // Layer 1: h1[n][o] = relu(b1 + x[n]·w1x + agg[n]·W1k[o])
  {
    Frag8 A0, A1;
    A0.f = *(const f16x8*)(AggL + r * 72 + q * 8);
    A1.f = *(const f16x8*)(AggL + r * 72 + 32 + q * 8);
    f32x4 d = {b1o, b1o, b1o, b1o};
    d = MFMA16(A0.f, B1[0].f, d);
    d = MFMA16(A1.f, B1[1].f, d);
#pragma unroll
    for (int reg = 0; reg < 4; ++reg) {
      const int n = q * 4 + reg;
      const float4 x = Xl[n];
      const float hv = d[reg] + x.x*w1x.x + x.y*w1x.y + x.z*w1x.z + x.w*w1x.w;
      H1L[n * 72 + o] = (_Float16)fmaxf(hv, 0.f);
    }
  }
  __syncthreads();

  // Layer 2: h2 = relu(b2 + h1·W2o^T)
  {
    Frag8 A0, A1;
    A0.f = *(const f16x8*)(H1L + r * 72 + q * 8);
    A1.f = *(const f16x8*)(H1L + r * 72 + 32 + q * 8);
    f32x4 d = {b2o, b2o, b2o, b2o};
    d = MFMA16(A0.f, B2[0].f, d);
    d = MFMA16(A1.f, B2[1].f, d);
#pragma unroll
    for (int reg = 0; reg < 4; ++reg) {
      const int n = q * 4 + reg;
      H2L[n * 72 + o] = (_Float16)fmaxf(d[reg], 0.f);
    }
  }
  __syncthreads();

  // Layer 3 (wave 0): delta[n][dm] = b3[dm] + h2[n]·W3[dm]; out = x + delta
  if (w == 0) {
    Frag8 B3[2];
#pragma unroll
    for (int ks = 0; ks < 2; ++ks) {
      const float* p3 = out3_w + (r & 3) * 64 + ks * 32 + q * 8;
      const float4 c0 = *(const float4*)p3;
      const float4 c1 = *(const float4*)(p3 + 4);
      B3[ks].u[0] = pk16(c0.x, c0.y); B3[ks].u[1] = pk16(c0.z, c0.w);
      B3[ks].u[2] = pk16(c1.x, c1.y); B3[ks].u[3] = pk16(c1.z, c1.w);
    }
    Frag8 A0, A1;
    A0.f = *(const f16x8*)(H2L + r * 72 + q * 8);
    A1.f = *(const f16x8*)(H2L + r * 72 + 32 + q * 8);
    const float b3o = out3_b[r & 3];
    f32x4 d = {b3o, b3o, b3o, b3o};
    d = MFMA16(A0.f, B3[0].f, d);
    d = MFMA16(A1.f, B3[1].f, d);
    if (r < 4) {  // valid cols; rows q*4+reg all valid
      const float* xf = (const float*)Xl;
#pragma unroll
      for (int reg = 0; reg < 4; ++reg) {
        const int n = q * 4 + reg;
        out[((b * NN + n_base + n) * NTO + t) * ND + r] = xf[n * 4 + r] + d[reg];
      }
    }
  }
}

extern "C" void kernel_launch(void* const* d_in, const int* in_sizes, int n_in,
                              void* d_out, int out_size, void* d_ws, size_t ws_size,
                              hipStream_t stream) {
  const float* inputs   = (const float*)d_in[0];
  const float* rel_type = (const float*)d_in[1];
  const float* fc1_w  = (const float*)d_in[4];
  const float* fc1_b  = (const float*)d_in[5];
  const float* fc2_w  = (const float*)d_in[6];
  const float* fc2_b  = (const float*)d_in[7];
  const float* out1_w = (const float*)d_in[8];
  const float* out1_b = (const float*)d_in[9];
  const float* out2_w = (const float*)d_in[10];
  const float* out2_b = (const float*)d_in[11];
  const float* out3_w = (const float*)d_in[12];
  const float* out3_b = (const float*)d_in[13];
  float* out = (float*)d_out;

  nri_fused_kernel<<<NB * NTO * 4, 256, 0, stream>>>(
      inputs, rel_type, fc1_w, fc1_b, fc2_w, fc2_b,
      out1_w, out1_b, out2_w, out2_b, out3_w, out3_b, out);
}